// Round 5
// baseline (144.183 us; speedup 1.0000x reference)
//
#include <hip/hip_runtime.h>

#define UNITS 256
#define NB 501               // num buckets
#define STEPF 0.05f
#define LBF -17.0f
#define UBF 8.0f
#define RESIDUEF -17.05f     // LB - STEP
#define LOG2E 1.4426950408889634f

#define WLO 192              // hot-window low bucket (x < -7.45 is cold)
#define WSZ 256              // window [192,448); P(outside) ~ 1e-7 of elements
#define UPB 16               // units per block
#define PADF2 257            // LDS row stride in float2 (odd -> pair spread)
#define THREADS 512
#define ROWS_PB 1024         // grid = 16 * 64 = 1024 blocks

// ---------------------------------------------------------------------------
// Kernel 1: full fused table -> d_ws (1.03 MB, L2-resident).
//   w  = relu(v[u,j])
//   C  = STEP*excl_cumsum(w)[j] + RESIDUE + b[u] - j*STEP*w
//   store (C*log2e, w*log2e):  sigmoid = rcp(1 + exp2(-(C2 + t*w2))),
//   t = clamp(x)+17.05.  One wave per unit, 8 buckets/lane.
// ---------------------------------------------------------------------------
__global__ __launch_bounds__(256) void build_table_kernel(
    const float* __restrict__ v, const float* __restrict__ b,
    float2* __restrict__ gtab) {
  const int lane = threadIdx.x & 63;
  const int wave = threadIdx.x >> 6;
  const int u = blockIdx.x * 4 + wave;
  if (u >= UNITS) return;

  const float* vu = v + u * NB;
  float w[8], pref[8];
  float run = 0.0f;
#pragma unroll
  for (int k = 0; k < 8; ++k) {
    const int j = lane * 8 + k;
    const float wv = (j < NB) ? fmaxf(vu[j], 0.0f) : 0.0f;
    w[k] = wv;
    pref[k] = run;  // exclusive within-lane prefix
    run += wv;
  }
  float s = run;    // inclusive wave scan of per-lane sums
#pragma unroll
  for (int d = 1; d < 64; d <<= 1) {
    const float o = __shfl_up(s, d, 64);
    if (lane >= d) s += o;
  }
  const float base = s - run;  // exclusive lane base
  const float off = RESIDUEF + b[u];
#pragma unroll
  for (int k = 0; k < 8; ++k) {
    const int j = lane * 8 + k;
    if (j < NB) {
      const float C = STEPF * (base + pref[k]) + off - (float)j * STEPF * w[k];
      gtab[u * NB + j] = make_float2(C * LOG2E, w[k] * LOG2E);
    }
  }
}

// ---------------------------------------------------------------------------
// Kernel 2: stream x -> out.  Per block: 16 units x 1024 rows.
// MLP fix (R4's failed): issue all 8 float4 row-loads, then __syncthreads().
// Loads cannot sink across the barrier, so 8 loads/thread are in flight
// before the first s_waitcnt (R4: compiler sank them -> 1 in flight, 2.6 TB/s
// plateau).  LDS gather is a single ds_read_b64 from an interleaved float2
// table (R4's split-float layout doubled conflict cycles; revert to R3 form).
// ---------------------------------------------------------------------------
__global__ __launch_bounds__(THREADS, 8) void iso_main_kernel(
    const float* __restrict__ x, const float2* __restrict__ gtab,
    float* __restrict__ out) {
  __shared__ float2 tab[UPB * PADF2];  // 32896 B -> 4 blocks/CU

  const int bu = blockIdx.x & (UNITS / UPB - 1);  // unit tile 0..15
  const int bb = blockIdx.x >> 4;                 // batch tile 0..63
  const int u0 = bu * UPB;

  // ---- stage hot window (coalesced reads, conflict-free writes) ----
  for (int i = threadIdx.x; i < UPB * WSZ; i += THREADS) {
    const int ul = i >> 8;            // WSZ == 256
    const int j = i & (WSZ - 1);
    tab[ul * PADF2 + j] = gtab[(u0 + ul) * NB + WLO + j];
  }

  // ---- issue all 8 x-loads BEFORE the barrier (8 outstanding/thread) ----
  const int r = threadIdx.x >> 2;     // 0..127
  const int q = threadIdx.x & 3;      // 0..3
  const float4* __restrict__ x4 = reinterpret_cast<const float4*>(x);
  float4* __restrict__ o4 = reinterpret_cast<float4*>(out);
  const int g0 = (bb * ROWS_PB + r) * (UNITS / 4) + (u0 >> 2) + q;

  float4 xv[8];
#pragma unroll
  for (int p = 0; p < 8; ++p) xv[p] = x4[g0 + p * 128 * (UNITS / 4)];

  __syncthreads();  // drains vmcnt with 8 loads in flight; also fences tab[]

  const int qbase = (4 * q) * PADF2;
#pragma unroll
  for (int p = 0; p < 8; ++p) {
    const float xs[4] = {xv[p].x, xv[p].y, xv[p].z, xv[p].w};
    float os[4];
#pragma unroll
    for (int k = 0; k < 4; ++k) {
      const float xc = fminf(fmaxf(xs[k], LBF + 1e-9f), UBF - 1e-9f);
      const float t = xc - LBF + STEPF;          // xc + 17.05, in (0, 25.05)
      int idx = (int)(t * 20.0f);                // 1/STEP == 20 exactly
      const unsigned iw = (unsigned)(idx - WLO);
      float2 cw;
      if (iw < WSZ) {                            // hot path: one ds_read_b64
        cw = tab[qbase + k * PADF2 + (int)iw];
      } else {                                   // ~1e-7 of elements
        idx = idx < 0 ? 0 : (idx > NB - 1 ? NB - 1 : idx);
        cw = gtab[(u0 + 4 * q + k) * NB + idx];
      }
      const float l2 = fmaf(t, cw.y, cw.x);      // log2e * logit
      const float e = __builtin_amdgcn_exp2f(-l2);
      os[k] = __builtin_amdgcn_rcpf(1.0f + e);
    }
    o4[g0 + p * 128 * (UNITS / 4)] = make_float4(os[0], os[1], os[2], os[3]);
  }
}

extern "C" void kernel_launch(void* const* d_in, const int* in_sizes, int n_in,
                              void* d_out, int out_size, void* d_ws,
                              size_t ws_size, hipStream_t stream) {
  const float* x = (const float*)d_in[0];   // (65536, 256)
  const float* v = (const float*)d_in[1];   // (256, 501)
  const float* b = (const float*)d_in[2];   // (256,)
  float* out = (float*)d_out;               // (65536, 256)
  float2* gtab = (float2*)d_ws;             // 256*501*8 B = 1.03 MB

  build_table_kernel<<<64, 256, 0, stream>>>(v, b, gtab);

  const int rows = out_size / UNITS;                  // 65536
  const int grid = (UNITS / UPB) * (rows / ROWS_PB);  // 16 * 64 = 1024
  iso_main_kernel<<<grid, THREADS, 0, stream>>>(x, gtab, out);
}

// Round 6
// 143.970 us; speedup vs baseline: 1.0015x; 1.0015x over previous
//
#include <hip/hip_runtime.h>

#define UNITS 256
#define NB 501               // num buckets
#define STEPF 0.05f
#define LBF -17.0f
#define UBF 8.0f
#define RESIDUEF -17.05f     // LB - STEP
#define LOG2E 1.4426950408889634f

#define WLO 192              // hot-window low bucket (x < -7.45 is cold)
#define WSZ 256              // window [192,448); P(outside) ~ 1e-7 of elements
#define UPB 16               // units per block
#define PADF2 257            // LDS row stride in float2 (odd -> pair spread)
#define THREADS 512
#define ROWS_PB 1024         // grid = 16 * 64 = 1024 blocks

// ---------------------------------------------------------------------------
// Kernel 1: full fused table -> d_ws (1.03 MB, L2-resident).
//   w  = relu(v[u,j])
//   C  = STEP*excl_cumsum(w)[j] + RESIDUE + b[u] - j*STEP*w
//   store (C*log2e, w*log2e):  sigmoid = rcp(1 + exp2(-(C2 + t*w2))),
//   t = clamp(x)+17.05.  One wave per unit, 8 buckets/lane.
// ---------------------------------------------------------------------------
__global__ __launch_bounds__(256) void build_table_kernel(
    const float* __restrict__ v, const float* __restrict__ b,
    float2* __restrict__ gtab) {
  const int lane = threadIdx.x & 63;
  const int wave = threadIdx.x >> 6;
  const int u = blockIdx.x * 4 + wave;
  if (u >= UNITS) return;

  const float* vu = v + u * NB;
  float w[8], pref[8];
  float run = 0.0f;
#pragma unroll
  for (int k = 0; k < 8; ++k) {
    const int j = lane * 8 + k;
    const float wv = (j < NB) ? fmaxf(vu[j], 0.0f) : 0.0f;
    w[k] = wv;
    pref[k] = run;  // exclusive within-lane prefix
    run += wv;
  }
  float s = run;    // inclusive wave scan of per-lane sums
#pragma unroll
  for (int d = 1; d < 64; d <<= 1) {
    const float o = __shfl_up(s, d, 64);
    if (lane >= d) s += o;
  }
  const float base = s - run;  // exclusive lane base
  const float off = RESIDUEF + b[u];
#pragma unroll
  for (int k = 0; k < 8; ++k) {
    const int j = lane * 8 + k;
    if (j < NB) {
      const float C = STEPF * (base + pref[k]) + off - (float)j * STEPF * w[k];
      gtab[u * NB + j] = make_float2(C * LOG2E, w[k] * LOG2E);
    }
  }
}

// ---------------------------------------------------------------------------
// Kernel 2: stream x -> out.  Per block: 16 units x 1024 rows.
// MLP: issue all 8 float4 row-loads before __syncthreads(); a single empty
// asm volatile with all 32 components as "+v" operands pins the results as
// data inputs, so the scheduler CANNOT sink the loads into the consume loop
// (R4/R5 failure mode: VGPR=28 proved sinking -> 1 load in flight -> 2.5 TB/s
// latency plateau).  LDS gather: one ds_read_b64 from interleaved float2
// table, odd row stride 257.
// ---------------------------------------------------------------------------
__global__ __launch_bounds__(THREADS, 8) void iso_main_kernel(
    const float* __restrict__ x, const float2* __restrict__ gtab,
    float* __restrict__ out) {
  __shared__ float2 tab[UPB * PADF2];  // 32896 B -> 4 blocks/CU

  const int bu = blockIdx.x & (UNITS / UPB - 1);  // unit tile 0..15
  const int bb = blockIdx.x >> 4;                 // batch tile 0..63
  const int u0 = bu * UPB;

  // ---- stage hot window (coalesced reads, conflict-free writes) ----
  for (int i = threadIdx.x; i < UPB * WSZ; i += THREADS) {
    const int ul = i >> 8;            // WSZ == 256
    const int j = i & (WSZ - 1);
    tab[ul * PADF2 + j] = gtab[(u0 + ul) * NB + WLO + j];
  }

  // ---- issue all 8 x-loads BEFORE the barrier (8 outstanding/thread) ----
  const int r = threadIdx.x >> 2;     // 0..127
  const int q = threadIdx.x & 3;      // 0..3
  const float4* __restrict__ x4 = reinterpret_cast<const float4*>(x);
  float4* __restrict__ o4 = reinterpret_cast<float4*>(out);
  const int g0 = (bb * ROWS_PB + r) * (UNITS / 4) + (u0 >> 2) + q;

  float4 xv[8];
#pragma unroll
  for (int p = 0; p < 8; ++p) xv[p] = x4[g0 + p * 128 * (UNITS / 4)];

  __syncthreads();  // barrier drains vmcnt with all 8 loads in flight

  // Pin: all 32 loaded components are data inputs to this (empty) asm, so
  // the loads cannot sink below it.  This is the MLP guarantee.
  asm volatile(""
               : "+v"(xv[0].x), "+v"(xv[0].y), "+v"(xv[0].z), "+v"(xv[0].w),
                 "+v"(xv[1].x), "+v"(xv[1].y), "+v"(xv[1].z), "+v"(xv[1].w),
                 "+v"(xv[2].x), "+v"(xv[2].y), "+v"(xv[2].z), "+v"(xv[2].w),
                 "+v"(xv[3].x), "+v"(xv[3].y), "+v"(xv[3].z), "+v"(xv[3].w),
                 "+v"(xv[4].x), "+v"(xv[4].y), "+v"(xv[4].z), "+v"(xv[4].w),
                 "+v"(xv[5].x), "+v"(xv[5].y), "+v"(xv[5].z), "+v"(xv[5].w),
                 "+v"(xv[6].x), "+v"(xv[6].y), "+v"(xv[6].z), "+v"(xv[6].w),
                 "+v"(xv[7].x), "+v"(xv[7].y), "+v"(xv[7].z), "+v"(xv[7].w));

  const int qbase = (4 * q) * PADF2;
#pragma unroll
  for (int p = 0; p < 8; ++p) {
    const float xs[4] = {xv[p].x, xv[p].y, xv[p].z, xv[p].w};
    float os[4];
#pragma unroll
    for (int k = 0; k < 4; ++k) {
      const float xc = fminf(fmaxf(xs[k], LBF + 1e-9f), UBF - 1e-9f);
      const float t = xc - LBF + STEPF;          // xc + 17.05, in (0, 25.05)
      int idx = (int)(t * 20.0f);                // 1/STEP == 20 exactly
      const unsigned iw = (unsigned)(idx - WLO);
      float2 cw;
      if (iw < WSZ) {                            // hot path: one ds_read_b64
        cw = tab[qbase + k * PADF2 + (int)iw];
      } else {                                   // ~1e-7 of elements
        idx = idx < 0 ? 0 : (idx > NB - 1 ? NB - 1 : idx);
        cw = gtab[(u0 + 4 * q + k) * NB + idx];
      }
      const float l2 = fmaf(t, cw.y, cw.x);      // log2e * logit
      const float e = __builtin_amdgcn_exp2f(-l2);
      os[k] = __builtin_amdgcn_rcpf(1.0f + e);
    }
    o4[g0 + p * 128 * (UNITS / 4)] = make_float4(os[0], os[1], os[2], os[3]);
  }
}

extern "C" void kernel_launch(void* const* d_in, const int* in_sizes, int n_in,
                              void* d_out, int out_size, void* d_ws,
                              size_t ws_size, hipStream_t stream) {
  const float* x = (const float*)d_in[0];   // (65536, 256)
  const float* v = (const float*)d_in[1];   // (256, 501)
  const float* b = (const float*)d_in[2];   // (256,)
  float* out = (float*)d_out;               // (65536, 256)
  float2* gtab = (float2*)d_ws;             // 256*501*8 B = 1.03 MB

  build_table_kernel<<<64, 256, 0, stream>>>(v, b, gtab);

  const int rows = out_size / UNITS;                  // 65536
  const int grid = (UNITS / UPB) * (rows / ROWS_PB);  // 16 * 64 = 1024
  iso_main_kernel<<<grid, THREADS, 0, stream>>>(x, gtab, out);
}

// Round 7
// 133.820 us; speedup vs baseline: 1.0774x; 1.0759x over previous
//
#include <hip/hip_runtime.h>

#define UNITS 256
#define NB 501               // num buckets
#define STEPF 0.05f
#define LBF -17.0f
#define UBF 8.0f
#define RESIDUEF -17.05f     // LB - STEP
#define LOG2E 1.4426950408889634f

#define WLO 192              // hot-window low bucket (x < -7.45 is cold)
#define WSZ 256              // window [192,448); P(outside) ~ 1e-7 of elements
#define UPB 64               // units per block -> wave x-loads are 4x256B
                             // contiguous runs (R2..R6 plateau theory: 16x64B
                             // scattered segments halve HBM efficiency)
#define PADF2 257            // LDS row stride in float2
#define THREADS 1024         // 16 waves; 1 block/CU (LDS-capped)
#define ROWS_PB 1024         // grid = 4 unit-tiles * 64 row-tiles = 256 blocks
#define CHUNKS 16            // 16 chunks of 64 rows; depth-4 register ring
#define RDEPTH 4

// ---------------------------------------------------------------------------
// Kernel 1: full fused table -> d_ws (1.03 MB, L2/L3-resident).
//   w  = relu(v[u,j])
//   C  = STEP*excl_cumsum(w)[j] + RESIDUE + b[u] - j*STEP*w
//   store (C*log2e, w*log2e):  sigmoid = rcp(1 + exp2(-(C2 + t*w2))),
//   t = clamp(x)+17.05.  One wave per unit, 8 buckets/lane.
// ---------------------------------------------------------------------------
__global__ __launch_bounds__(256) void build_table_kernel(
    const float* __restrict__ v, const float* __restrict__ b,
    float2* __restrict__ gtab) {
  const int lane = threadIdx.x & 63;
  const int wave = threadIdx.x >> 6;
  const int u = blockIdx.x * 4 + wave;
  if (u >= UNITS) return;

  const float* vu = v + u * NB;
  float w[8], pref[8];
  float run = 0.0f;
#pragma unroll
  for (int k = 0; k < 8; ++k) {
    const int j = lane * 8 + k;
    const float wv = (j < NB) ? fmaxf(vu[j], 0.0f) : 0.0f;
    w[k] = wv;
    pref[k] = run;  // exclusive within-lane prefix
    run += wv;
  }
  float s = run;    // inclusive wave scan of per-lane sums
#pragma unroll
  for (int d = 1; d < 64; d <<= 1) {
    const float o = __shfl_up(s, d, 64);
    if (lane >= d) s += o;
  }
  const float base = s - run;  // exclusive lane base
  const float off = RESIDUEF + b[u];
#pragma unroll
  for (int k = 0; k < 8; ++k) {
    const int j = lane * 8 + k;
    if (j < NB) {
      const float C = STEPF * (base + pref[k]) + off - (float)j * STEPF * w[k];
      gtab[u * NB + j] = make_float2(C * LOG2E, w[k] * LOG2E);
    }
  }
}

// ---------------------------------------------------------------------------
// Kernel 2: stream x -> out.  Per block: 64 units x 1024 rows, 1024 threads.
// LDS: 64-unit hot window, 64*257*8 = 131584 B -> exactly 1 block/CU.
// Load mapping: lane l -> (row_off = l>>4, float4-col = l&15), so each
// wave-load = 4 rows x 256 B CONTIGUOUS runs (vs R2..R6's 16 x 64 B scatter).
// 16 waves run independent depth-4-ring pipelines after a single barrier:
// no per-chunk phase lock, continuous memory pressure.
// ---------------------------------------------------------------------------
__global__ __launch_bounds__(THREADS, 4) void iso_main_kernel(
    const float* __restrict__ x, const float2* __restrict__ gtab,
    float* __restrict__ out) {
  __shared__ float2 tab[UPB * PADF2];  // 131584 B

  const int bu = blockIdx.x & 3;            // unit tile 0..3 (UPB=64)
  const int bb = blockIdx.x >> 2;           // batch tile 0..63
  const int u0 = bu * UPB;

  // ---- stage hot window: 64 units x 256 buckets, 16 entries/thread ----
#pragma unroll
  for (int i = threadIdx.x; i < UPB * WSZ; i += THREADS) {
    const int ul = i >> 8;                  // WSZ == 256
    const int j = i & (WSZ - 1);
    tab[ul * PADF2 + j] = gtab[(u0 + ul) * NB + WLO + j];
  }
  __syncthreads();                          // the only barrier

  // ---- stream: 16 chunks of 64 rows, depth-4 register ring ----
  const int lane = threadIdx.x & 63;
  const int wv = threadIdx.x >> 6;          // wave 0..15
  const int rowoff = wv * 4 + (lane >> 4);  // 0..63 within chunk
  const int col4 = lane & 15;               // float4 col within 64-unit span
  const float4* __restrict__ x4 = reinterpret_cast<const float4*>(x);
  float4* __restrict__ o4 = reinterpret_cast<float4*>(out);
  // float4 linear index; row stride = 64 float4
  const int g0 = (bb * ROWS_PB + rowoff) * (UNITS / 4) + bu * 16 + col4;
  const int gstep = 64 * (UNITS / 4);       // 64 rows per chunk
  const int qbase = (col4 * 4) * PADF2;     // LDS base for this thread's units

  float4 xv[RDEPTH];
#pragma unroll
  for (int c = 0; c < RDEPTH; ++c) xv[c] = x4[g0 + c * gstep];

#pragma unroll
  for (int c = 0; c < CHUNKS; ++c) {
    const float4 cur = xv[c & (RDEPTH - 1)];
    if (c + RDEPTH < CHUNKS)
      xv[c & (RDEPTH - 1)] = x4[g0 + (c + RDEPTH) * gstep];

    const float xs[4] = {cur.x, cur.y, cur.z, cur.w};
    float os[4];
#pragma unroll
    for (int k = 0; k < 4; ++k) {
      const float xc = fminf(fmaxf(xs[k], LBF + 1e-9f), UBF - 1e-9f);
      const float t = xc - LBF + STEPF;     // xc + 17.05, in (0, 25.05)
      int idx = (int)(t * 20.0f);           // 1/STEP == 20 exactly
      const unsigned iw = (unsigned)(idx - WLO);
      float2 cw;
      if (iw < WSZ) {                       // hot path: one ds_read_b64
        cw = tab[qbase + k * PADF2 + (int)iw];
      } else {                              // ~1e-7 of elements
        idx = idx < 0 ? 0 : (idx > NB - 1 ? NB - 1 : idx);
        cw = gtab[(u0 + col4 * 4 + k) * NB + idx];
      }
      const float l2 = fmaf(t, cw.y, cw.x); // log2e * logit
      const float e = __builtin_amdgcn_exp2f(-l2);
      os[k] = __builtin_amdgcn_rcpf(1.0f + e);
    }
    o4[g0 + c * gstep] = make_float4(os[0], os[1], os[2], os[3]);
  }
}

extern "C" void kernel_launch(void* const* d_in, const int* in_sizes, int n_in,
                              void* d_out, int out_size, void* d_ws,
                              size_t ws_size, hipStream_t stream) {
  const float* x = (const float*)d_in[0];   // (65536, 256)
  const float* v = (const float*)d_in[1];   // (256, 501)
  const float* b = (const float*)d_in[2];   // (256,)
  float* out = (float*)d_out;               // (65536, 256)
  float2* gtab = (float2*)d_ws;             // 256*501*8 B = 1.03 MB

  build_table_kernel<<<64, 256, 0, stream>>>(v, b, gtab);

  const int rows = out_size / UNITS;                  // 65536
  const int grid = (UNITS / UPB) * (rows / ROWS_PB);  // 4 * 64 = 256
  iso_main_kernel<<<grid, THREADS, 0, stream>>>(x, gtab, out);
}